// Round 7
// baseline (465.045 us; speedup 1.0000x reference)
//
#include <hip/hip_runtime.h>
#include <hip/hip_bf16.h>
#include <cstdint>
#include <cstddef>

typedef __bf16 bf16;
typedef __bf16 bf16x8 __attribute__((ext_vector_type(8)));
typedef float f32x4 __attribute__((ext_vector_type(4)));

// async global->LDS DMA, 16B per lane; lds dest wave-uniform base + lane*16
__device__ __forceinline__ void gload_lds16(const bf16* g, bf16* l) {
    __builtin_amdgcn_global_load_lds((const __attribute__((address_space(1))) void*)g,
                                     (__attribute__((address_space(3))) void*)l, 16, 0, 0);
}

// valid-tap mask for a 128-row pos-major M-block (rows pos*1088+box)
__device__ __forceinline__ int block_tap_mask(int y) {
    int lo = (y * 128) / 1088;
    int hiRow = y * 128 + 127; if (hiRow > 9791) hiRow = 9791;
    int hi = hiRow / 1088;
    int msk = 0;
    for (int pos = lo; pos <= hi; ++pos) {
        int oy = pos / 3, ox = pos - oy * 3;
        int ym = oy == 0 ? 6 : (oy == 1 ? 7 : 3);   // valid ty bits
        int xm = ox == 0 ? 6 : (ox == 1 ? 7 : 3);   // valid tx bits
        #pragma unroll
        for (int ty = 0; ty < 3; ty++)
            #pragma unroll
            for (int tx = 0; tx < 3; tx++)
                if (((ym >> ty) & 1) & ((xm >> tx) & 1))
                    msk |= 1 << (ty * 3 + tx);
    }
    return msk;
}

// ---------------- weight repack (coalesced): w[OC][IC][NT] -> out[OC][NT*IC] bf16
template <int NT>
__global__ void __launch_bounds__(256) repack_w(const float* __restrict__ w, bf16* __restrict__ out,
                                                int OC, int IC) {
    int idx = blockIdx.x * 256 + threadIdx.x;
    if (idx >= OC * IC) return;
    int oc = idx / IC;
    int ic = idx - oc * IC;
    const float* src = w + (size_t)idx * NT;
    #pragma unroll
    for (int t = 0; t < NT; t++)
        out[(size_t)oc * NT * IC + t * IC + ic] = (bf16)src[t];
}

// ---------------- merged conv1+conv2 weight repack (one dispatch)
__global__ void __launch_bounds__(256) repack_w9_both(const float* __restrict__ wa, bf16* __restrict__ oa,
                                                      const float* __restrict__ wb, bf16* __restrict__ ob) {
    int idx = blockIdx.x * 256 + threadIdx.x;
    if (idx < 512 * 1024) {
        int oc = idx >> 10, ic = idx & 1023;
        const float* src = wa + (size_t)idx * 9;
        #pragma unroll
        for (int t = 0; t < 9; t++)
            oa[(size_t)oc * 9216 + t * 1024 + ic] = (bf16)src[t];
    } else {
        int k = idx - 512 * 1024;
        if (k < 256 * 512) {
            int oc = k >> 9, ic = k & 511;
            const float* src = wb + (size_t)k * 9;
            #pragma unroll
            for (int t = 0; t < 9; t++)
                ob[(size_t)oc * 4608 + t * 512 + ic] = (bf16)src[t];
        }
    }
}

// ---------------- fc1_w [2304][1024] -> fc1t [1024][2304] bf16 (LDS tiled)
__global__ void __launch_bounds__(256) transpose_fc1(const float* __restrict__ w, bf16* __restrict__ out) {
    __shared__ float t[32][33];
    int iT = blockIdx.x * 32;
    int oT = blockIdx.y * 32;
    int tx = threadIdx.x, ty = threadIdx.y;   // 32 x 8
    #pragma unroll
    for (int j = 0; j < 4; j++)
        t[ty + j * 8][tx] = w[(size_t)(iT + ty + j * 8) * 1024 + oT + tx];
    __syncthreads();
    #pragma unroll
    for (int j = 0; j < 4; j++)
        out[(size_t)(oT + ty + j * 8) * 2304 + iT + tx] = (bf16)t[tx][ty + j * 8];
}

// ---------------- unified setup: per-tap rowbase tables (POS-MAJOR M), tap masks,
// static LPT task tables, zero pages, BN folds, w2t.
// conv1 grouping: J1 = ceil(T/3) (2-3 taps, 32-48 K-steps) -> 164 entries x 4 nt = 656
// conv2 grouping: J2 = ceil(T/4) (3-4 taps, 24-32 K-steps) -> 130 entries x 2 nt = 260
// Task order is XCD-interleaved: all nt-variants of one (y,j) share blockIdx%8 ->
// same XCD L2 caches the A-tile across n-tiles. LPT (heavy-first) kept within XCD.
// task pack: (y<<5)|(j<<2)|nt
__global__ void __launch_bounds__(256) setup_all(int* __restrict__ rb1t, int* __restrict__ rb2t,
                                                 int* __restrict__ rb1dg, int* __restrict__ rbid,
                                                 int* __restrict__ tapmask,
                                                 int* __restrict__ tasks1, int* __restrict__ tasks2,
                                                 const int* __restrict__ pidx,
                                                 bf16* __restrict__ zp1, bf16* __restrict__ zp2,
                                                 bf16* __restrict__ zp3,
                                                 const float* g1, const float* b1, const float* m1, const float* v1,
                                                 const float* g2, const float* b2, const float* m2, const float* v2,
                                                 float* __restrict__ s1, float* __restrict__ t1,
                                                 float* __restrict__ s2, float* __restrict__ t2,
                                                 const float* __restrict__ fc2_w, bf16* __restrict__ w2t) {
    int m = blockIdx.x * 256 + threadIdx.x;
    if (m < 9 * 9856) {
        int tap = m / 9856, r = m - tap * 9856;
        int mm = r < 9792 ? r : 0;
        int pos = mm / 1088, img = mm - pos * 1088;     // pos-major decode
        int oy = pos / 3, ox = pos - oy * 3;
        int ty = tap / 3, tx = tap - ty * 3;
        int iy = oy + ty - 1, ix = ox + tx - 1;
        bool valid = (iy >= 0) & (iy < 3) & (ix >= 0) & (ix < 3);
        int cell = iy * 3 + ix;
        rb1t[m] = valid ? 1024 + (img * 9 + cell) * 1024 : 0;     // a1c phys: [box][cell][1024]
        rb2t[m] = valid ? 512 + (cell * 1088 + img) * 512 : 0;    // a2c: pos-major [cell*1088+box][512]
    }
    if (m < 77) tapmask[m] = block_tap_mask(m);
    // ---- block 0: build static LPT-sorted, XCD-interleaved task tables
    if (blockIdx.x == 0) {
        __shared__ int sT[77], sB1[78], sB2[78];
        __shared__ int e1y[164], e1j[164], e1w[164];
        __shared__ int e2y[130], e2j[130], e2w[130];
        int t = threadIdx.x;
        if (t < 77) sT[t] = __popc(block_tap_mask(t));
        __syncthreads();
        if (t == 0) {
            int a1 = 0, a2 = 0;
            for (int y = 0; y < 77; ++y) {
                sB1[y] = a1; a1 += (sT[y] + 2) / 3;
                sB2[y] = a2; a2 += (sT[y] + 3) / 4;
            }
            sB1[77] = a1;   // == 164
            sB2[77] = a2;   // == 130
        }
        __syncthreads();
        if (t < 77) {
            int T = sT[t];
            int J1 = (T + 2) / 3, J2 = (T + 3) / 4;
            int w1[3] = {0, 0, 0}, w2[3] = {0, 0, 0};
            for (int o = 0; o < T; ++o) { w1[o * J1 / T]++; w2[o * J2 / T]++; }
            for (int jj = 0; jj < J1; ++jj) {
                int e = sB1[t] + jj;
                e1y[e] = t; e1j[e] = jj; e1w[e] = w1[jj];
            }
            for (int jj = 0; jj < J2; ++jj) {
                int e = sB2[t] + jj;
                e2y[e] = t; e2j[e] = jj; e2w[e] = w2[jj];
            }
        }
        __syncthreads();
        if (t < 164) {
            int wv = e1w[t], rank = 0;
            for (int e2i = 0; e2i < 164; ++e2i)
                rank += (e1w[e2i] > wv) | ((e1w[e2i] == wv) & (e2i < t));
            int pk = (e1y[t] << 5) | (e1j[t] << 2);
            #pragma unroll
            for (int nt = 0; nt < 4; ++nt) {
                int idx = (rank < 160) ? ((rank & 7) + (((rank >> 3) * 4 + nt) << 3))
                                       : (640 + (rank - 160) * 4 + nt);
                tasks1[idx] = pk | nt;
            }
        }
        if (t < 130) {
            int wv = e2w[t], rank = 0;
            for (int e2i = 0; e2i < 130; ++e2i)
                rank += (e2w[e2i] > wv) | ((e2w[e2i] == wv) & (e2i < t));
            int pk = (e2y[t] << 5) | (e2j[t] << 2);
            #pragma unroll
            for (int nt = 0; nt < 2; ++nt) {
                int idx = (rank < 128) ? ((rank & 7) + (((rank >> 3) * 2 + nt) << 3))
                                       : (256 + (rank - 128) * 2 + nt);
                tasks2[idx] = pk | nt;
            }
        }
    }
    if (m < 3 * 1024) {
        int tap = m / 1024, r = m - tap * 1024;
        int b = r >> 4;
        int p = pidx[r];
        int tt = b + tap - 1;
        bool valid = (tt >= 0) & (tt < 64);
        rb1dg[m] = valid ? 2304 + (p * 64 + tt) * 2304 : 0;
    }
    if (m < 1024) rbid[m] = m * 2304;
    if (m < 30 * 1024) {
        int n = m / 1024, k = m - n * 1024;
        w2t[m] = (bf16)fc2_w[(size_t)k * 30 + n];
    }
    if (m < 1024) zp1[m] = (bf16)0.f;
    if (m < 512)  zp2[m] = (bf16)0.f;
    if (m < 2304) zp3[m] = (bf16)0.f;
    if (m < 512) {
        float sc = g1[m] * rsqrtf(v1[m] + 1e-5f);
        s1[m] = sc; t1[m] = b1[m] - m1[m] * sc;
    } else if (m < 768) {
        int i = m - 512;
        float sc = g2[i] * rsqrtf(v2[i] + 1e-5f);
        s2[i] = sc; t2[i] = b2[i] - m2[i] * sc;
    }
}

// ---------------- fmap transpose to channels-last bf16
__global__ void __launch_bounds__(256) transpose_fmap(const float* __restrict__ fmap, bf16* __restrict__ fml) {
    __shared__ float t[32][33];
    int img = blockIdx.z;
    int hwT = blockIdx.x * 32;
    int cT  = blockIdx.y * 32;
    int tx = threadIdx.x, ty = threadIdx.y;
    #pragma unroll
    for (int j = 0; j < 4; j++) {
        int c = cT + ty + j * 8;
        int hw = hwT + tx;
        if (hw < 196)
            t[ty + j * 8][tx] = fmap[((size_t)img * 1024 + c) * 196 + hw];
    }
    __syncthreads();
    #pragma unroll
    for (int j = 0; j < 4; j++) {
        int hw = hwT + ty + j * 8;
        int c = cT + tx;
        if (hw < 196)
            fml[((size_t)img * 196 + hw) * 1024 + c] = (bf16)t[tx][ty + j * 8];
    }
}

// ---------------- roi_align (channels-last) -> a1c compact [1088][9][1024] (after 1024-elem zp)
__global__ void __launch_bounds__(128) roi_kernel2(const bf16* __restrict__ fml, const float* __restrict__ boxes,
                                                   bf16* __restrict__ a1c) {
    int box = blockIdx.x;
    int tid = threadIdx.x;
    float x1, y1, x2, y2;
    int img;
    if (box < 64) { img = box; x1 = 0.f; y1 = 0.f; x2 = 14.f; y2 = 14.f; }
    else {
        int ib = box - 64;
        img = ib >> 4;
        const float* bb = boxes + (size_t)ib * 4;
        x1 = bb[0]; y1 = bb[1]; x2 = bb[2]; y2 = bb[3];
    }
    float rw = fmaxf(x2 - x1, 1.f), rh = fmaxf(y2 - y1, 1.f);
    __shared__ float swy[6], swx[6];
    __shared__ int sy0[6], sx0[6];
    if (tid < 6) {
        int i = tid;
        float pos = ((float)i + 0.5f) * 0.5f;
        float yv = fminf(fmaxf(y1 + pos * (rh * (1.f / 3.f)), 0.f), 13.f);
        float y0 = floorf(yv);
        sy0[i] = (int)y0; swy[i] = yv - y0;
        float xv = fminf(fmaxf(x1 + pos * (rw * (1.f / 3.f)), 0.f), 13.f);
        float x0 = floorf(xv);
        sx0[i] = (int)x0; swx[i] = xv - x0;
    }
    __syncthreads();
    const bf16* base = fml + (size_t)img * 196 * 1024 + tid * 8;
    #pragma unroll
    for (int oy = 0; oy < 3; oy++) {
        #pragma unroll
        for (int ox = 0; ox < 3; ox++) {
            float acc[8];
            #pragma unroll
            for (int e = 0; e < 8; e++) acc[e] = 0.f;
            #pragma unroll
            for (int dy = 0; dy < 2; dy++) {
                int sy = 2 * oy + dy;
                int y0 = sy0[sy]; float wy = swy[sy];
                int y1i = min(y0 + 1, 13);
                #pragma unroll
                for (int dx = 0; dx < 2; dx++) {
                    int sx = 2 * ox + dx;
                    int x0 = sx0[sx]; float wx = swx[sx];
                    int x1i = min(x0 + 1, 13);
                    bf16x8 f00 = *(const bf16x8*)(base + (size_t)(y0 * 14 + x0) * 1024);
                    bf16x8 f01 = *(const bf16x8*)(base + (size_t)(y0 * 14 + x1i) * 1024);
                    bf16x8 f10 = *(const bf16x8*)(base + (size_t)(y1i * 14 + x0) * 1024);
                    bf16x8 f11 = *(const bf16x8*)(base + (size_t)(y1i * 14 + x1i) * 1024);
                    float w00 = (1.f - wy) * (1.f - wx), w01 = (1.f - wy) * wx;
                    float w10 = wy * (1.f - wx),         w11 = wy * wx;
                    #pragma unroll
                    for (int e = 0; e < 8; e++)
                        acc[e] += w00 * (float)f00[e] + w01 * (float)f01[e]
                                + w10 * (float)f10[e] + w11 * (float)f11[e];
                }
            }
            bf16x8 o;
            #pragma unroll
            for (int e = 0; e < 8; e++) o[e] = (bf16)(acc[e] * 0.25f);
            *(bf16x8*)(a1c + 1024 + ((size_t)box * 9 + oy * 3 + ox) * 1024 + tid * 8) = o;
        }
    }
}

// ---------------- behavior assembly -> asm3 compact [20][64][2304] (after 2304-elem zp)
__global__ void __launch_bounds__(256) assemble(const float* __restrict__ feat, const int* __restrict__ pidx,
                                                bf16* __restrict__ asm3) {
    int b = blockIdx.x;
    int p = blockIdx.y;
    __shared__ int idxs[16];
    if (threadIdx.x < 16) idxs[threadIdx.x] = pidx[b * 16 + threadIdx.x];
    __syncthreads();
    const float* g = feat + (size_t)b * 2304;
    for (int f = threadIdx.x; f < 2304; f += 256) {
        float v = g[f];
        #pragma unroll
        for (int n = 0; n < 16; n++)
            if (idxs[n] == p) v += feat[(size_t)(64 + b * 16 + n) * 2304 + f];
        asm3[2304 + ((size_t)p * 64 + b) * 2304 + f] = (bf16)v;
    }
}

// ---------------- implicit-GEMM MFMA: 128x128 tile, global_load_lds + XOR swizzle,
// per-tap row tables (zero rows -> zero page). 4 waves 2x2; wave 64x64
// (4x4 16x16x32, acc[4][4]); BK=64; split-K fp32 partials.
// MODE 0/1 (conv1/conv2): POS-MAJOR M + valid-tap skip, static LPT task per block.
// conv1: J1=ceil(T/3) (2-3 taps); conv2: J2=ceil(T/4) (3-4 taps). Slices j>=J not
// written (reducers gate by J). MODE 2/3: static grid (uniform K per block).
template <int MODE, int NSPLIT>
__global__ void __launch_bounds__(256) gemm_k(const bf16* __restrict__ A, const int* __restrict__ rowtab,
                                              const bf16* __restrict__ Bw, float* __restrict__ outp,
                                              const int* __restrict__ tapmask,
                                              const int* __restrict__ tasklist) {
    constexpr int K   = MODE == 0 ? 9216 : MODE == 1 ? 4608 : MODE == 2 ? 6912 : 2304;
    constexpr int N   = MODE == 0 ? 512  : MODE == 1 ? 256  : MODE == 2 ? 2304 : 1024;
    constexpr int Cin = MODE == 0 ? 1024 : MODE == 1 ? 512  : 2304;
    constexpr int M   = MODE <= 1 ? 9792 : 1024;
    constexpr int MT  = MODE <= 1 ? 9856 : 1024;   // table row stride
    constexpr bool MPAD = (M % 128) != 0;
    constexpr int KTS = (K / 64) / NSPLIT;

    const int tid = threadIdx.x;
    const int lane = tid & 63, wave = tid >> 6;
    const int q = lane >> 4, ln16 = lane & 15;
    const int wr = wave >> 1, wc = wave & 1;

    __shared__ __align__(16) bf16 As[128 * 64];
    __shared__ __align__(16) bf16 Bs[128 * 64];

    const int sr = lane >> 3;
    const int sc = ((lane & 7) ^ sr) * 8;    // XOR-permuted chunk offset (elems)

    int bm, bn, z;
    int mask = 0, T = 0, J = 0, jsel = 0;
    if constexpr (MODE <= 1) {
        const int pk = tasklist[blockIdx.x];
        const int y = pk >> 5;
        jsel = (pk >> 2) & 7;
        const int nt = pk & 3;
        bm = y * 128; bn = nt * 128; z = jsel;
        mask = tapmask[y];
        T = __popc(mask);
        J = MODE == 0 ? (T + 2) / 3 : (T + 3) / 4;
    } else {
        bm = blockIdx.y * 128;
        bn = blockIdx.x * 128;
        z = blockIdx.z;
    }

    const bf16* gB[4];
    #pragma unroll
    for (int u = 0; u < 4; u++)
        gB[u] = Bw + (size_t)(bn + wave * 32 + u * 8 + sr) * K + sc;

    f32x4 acc[4][4];
    #pragma unroll
    for (int mt = 0; mt < 4; mt++)
        #pragma unroll
        for (int nn = 0; nn < 4; nn++)
            acc[mt][nn] = (f32x4){0.f, 0.f, 0.f, 0.f};

    if constexpr (MODE <= 1) {
        int ord = 0;
        for (int tap = 0; tap < 9; ++tap) {
            if (!((mask >> tap) & 1)) continue;
            const int o = ord++;
            if (o * J / T != jsel) continue;
            int rbA[4];
            #pragma unroll
            for (int u = 0; u < 4; u++)
                rbA[u] = rowtab[tap * MT + bm + wave * 32 + u * 8 + sr];
            for (int kk = 0; kk < Cin / 64; ++kk) {
                const int aoff = kk * 64 + sc;
                const int k0 = tap * Cin + kk * 64;

                __syncthreads();
                #pragma unroll
                for (int u = 0; u < 4; u++)
                    gload_lds16(A + (size_t)(rbA[u] + aoff), As + (wave * 32 + u * 8) * 64);
                #pragma unroll
                for (int u = 0; u < 4; u++)
                    gload_lds16(gB[u] + k0, Bs + (wave * 32 + u * 8) * 64);
                __syncthreads();

                #pragma unroll
                for (int s = 0; s < 2; s++) {
                    bf16x8 af[4], bfr[4];
                    #pragma unroll
                    for (int mt = 0; mt < 4; mt++) {
                        int r = wr * 64 + mt * 16 + ln16;
                        af[mt] = *(const bf16x8*)(As + r * 64 + (((4 * s + q) ^ (ln16 & 7)) << 3));
                    }
                    #pragma unroll
                    for (int nn = 0; nn < 4; nn++) {
                        int r = wc * 64 + nn * 16 + ln16;
                        bfr[nn] = *(const bf16x8*)(Bs + r * 64 + (((4 * s + q) ^ (ln16 & 7)) << 3));
                    }
                    #pragma unroll
                    for (int mt = 0; mt < 4; mt++)
                        #pragma unroll
                        for (int nn = 0; nn < 4; nn++)
                            acc[mt][nn] = __builtin_amdgcn_mfma_f32_16x16x32_bf16(af[mt], bfr[nn], acc[mt][nn], 0, 0, 0);
                }
            }
        }
    } else {
        int rbA[4];
        int curtap = -1;
        for (int kt = z * KTS; kt < z * KTS + KTS; kt++) {
            const int k0 = kt * 64;
            const int tap = k0 / Cin;                 // wave-uniform
            const int inner = k0 - tap * Cin;
            if (tap != curtap) {
                curtap = tap;
                #pragma unroll
                for (int u = 0; u < 4; u++)
                    rbA[u] = rowtab[tap * MT + bm + wave * 32 + u * 8 + sr];
            }
            const int aoff = inner + sc;

            __syncthreads();
            #pragma unroll
            for (int u = 0; u < 4; u++)
                gload_lds16(A + (size_t)(rbA[u] + aoff), As + (wave * 32 + u * 8) * 64);
            #pragma unroll
            for (int u = 0; u < 4; u++)
                gload_lds16(gB[u] + k0, Bs + (wave * 32 + u * 8) * 64);
            __syncthreads();

            #pragma unroll
            for (int s = 0; s < 2; s++) {
                bf16x8 af[4], bfr[4];
                #pragma unroll
                for (int mt = 0; mt < 4; mt++) {
                    int r = wr * 64 + mt * 16 + ln16;
                    af[mt] = *(const bf16x8*)(As + r * 64 + (((4 * s + q) ^ (ln16 & 7)) << 3));
                }
                #pragma unroll
                for (int nn = 0; nn < 4; nn++) {
                    int r = wc * 64 + nn * 16 + ln16;
                    bfr[nn] = *(const bf16x8*)(Bs + r * 64 + (((4 * s + q) ^ (ln16 & 7)) << 3));
                }
                #pragma unroll
                for (int mt = 0; mt < 4; mt++)
                    #pragma unroll
                    for (int nn = 0; nn < 4; nn++)
                        acc[mt][nn] = __builtin_amdgcn_mfma_f32_16x16x32_bf16(af[mt], bfr[nn], acc[mt][nn], 0, 0, 0);
            }
        }
    }

    // epilogue: C/D layout col=lane&15, row=quad*4+reg; fp32 partials
    #pragma unroll
    for (int mt = 0; mt < 4; mt++) {
        int gmBase = bm + wr * 64 + mt * 16 + q * 4;
        #pragma unroll
        for (int r = 0; r < 4; r++) {
            int gm = gmBase + r;
            if (MPAD && gm >= M) continue;
            #pragma unroll
            for (int nn = 0; nn < 4; nn++) {
                int gn = bn + wc * 64 + nn * 16 + ln16;
                outp[((size_t)z * M + gm) * N + gn] = acc[mt][nn][r];
            }
        }
    }
}

// ---------------- conv2 reducer: per-cell block, coalesced + LDS transpose
// part2[<=3][9792][256] (POS-MAJOR rows: pos*1088+cell) -> feat[1088][2304] fp32
// with BN+leaky, f = oc*9+pos. Slice count per row = J2(y) = ceil(T/4) in {1,2,3}.
__global__ void __launch_bounds__(256) reduce0_tiled(const float* __restrict__ part,
                                                     float* __restrict__ feat,
                                                     const float* __restrict__ s2, const float* __restrict__ t2,
                                                     const int* __restrict__ tapm) {
    int c = blockIdx.x;            // cell 0..1087
    int t = threadIdx.x;           // oc
    float acc[9];
    #pragma unroll
    for (int r = 0; r < 9; r++) {
        int m = r * 1088 + c;
        int y = m >> 7;
        int J = (__popc(tapm[y]) + 3) / 4;           // 1, 2 or 3
        const float* p0 = part + (size_t)m * 256 + t;
        float v = p0[0];
        if (J >= 2) v += p0[(size_t)9792 * 256];
        if (J >= 3) v += p0[(size_t)2 * 9792 * 256];
        acc[r] = v;
    }
    float s = s2[t], b = t2[t];
    __shared__ float L[9 * 257];
    #pragma unroll
    for (int r = 0; r < 9; r++) {
        float v = acc[r] * s + b;
        v = v > 0.f ? v : 0.1f * v;
        L[r * 257 + t] = v;        // L[pos*257 + oc]
    }
    __syncthreads();
    float* fout = feat + (size_t)c * 2304;
    #pragma unroll
    for (int k = 0; k < 9; k++) {
        int f = t + k * 256;
        int oc = f / 9, pos = f - oc * 9;
        fout[f] = L[pos * 257 + oc];
    }
}

// ---------------- split-K reducers
// RMODE 1: conv1d -> xbuf bf16 (+bias, linear [m=(b,n)][oc]), S=3, M=1024 N=2304
// RMODE 2: fc1 -> hbuf bf16 (+bias, relu), S=4, M=1024 N=1024
// RMODE 3: conv1 -> a2c compact bf16 (BN+leaky, +zp offset), slices=J1(y) in {2,3}
template <int RMODE>
__global__ void __launch_bounds__(256) reduce_k(const float* __restrict__ part, void* __restrict__ outp,
                                                const float* __restrict__ c0, const float* __restrict__ c1,
                                                const int* __restrict__ tapm) {
    constexpr int M = RMODE == 1 ? 1024 : RMODE == 2 ? 1024 : 9792;
    constexpr int N = RMODE == 1 ? 2304 : RMODE == 2 ? 1024 : 512;
    constexpr int S = RMODE == 1 ? 3    : RMODE == 2 ? 4    : 2;
    int idx = blockIdx.x * 256 + threadIdx.x;
    if (idx >= M * N) return;
    int m = idx / N, n = idx - m * N;
    float v = 0.f;
    #pragma unroll
    for (int s = 0; s < S; s++) v += part[(size_t)s * M * N + idx];
    if constexpr (RMODE == 1) {
        v += c0[n];
        ((bf16*)outp)[idx] = (bf16)v;
    } else if constexpr (RMODE == 2) {
        v = fmaxf(v + c0[n], 0.f);
        ((bf16*)outp)[idx] = (bf16)v;
    } else {
        int y = m >> 7;
        int J = (__popc(tapm[y]) + 2) / 3;           // 2 or 3
        if (J == 3) v += part[(size_t)2 * M * N + idx];
        v = v * c0[n] + c1[n];
        v = v > 0.f ? v : 0.1f * v;
        ((bf16*)outp)[512 + (size_t)m * 512 + n] = (bf16)v;   // compact, after zp2
    }
}

// ---------------- fc2
__global__ void __launch_bounds__(256) fc2_kernel(const bf16* __restrict__ h, const bf16* __restrict__ w2t,
                                                  const float* __restrict__ b2, float* __restrict__ out) {
    int tid = threadIdx.x;
    int m = blockIdx.x * 8 + (tid >> 5);
    int n = tid & 31;
    int n2 = n < 30 ? n : 29;
    const bf16* hr = h + (size_t)m * 1024;
    const bf16* wr = w2t + (size_t)n2 * 1024;
    float acc = 0.f;
    for (int k = 0; k < 1024; k += 8) {
        bf16x8 hv = *(const bf16x8*)(hr + k);
        bf16x8 wv = *(const bf16x8*)(wr + k);
        #pragma unroll
        for (int e = 0; e < 8; e++) acc += (float)hv[e] * (float)wv[e];
    }
    if (n < 30) out[(size_t)m * 30 + n] = acc + b2[n];
}

extern "C" void kernel_launch(void* const* d_in, const int* in_sizes, int n_in,
                              void* d_out, int out_size, void* d_ws, size_t ws_size,
                              hipStream_t stream) {
    const float* fmap     = (const float*)d_in[0];
    const float* boxes    = (const float*)d_in[1];
    const int*   pidx     = (const int*)d_in[2];
    const float* conv1_w  = (const float*)d_in[3];
    const float* bn1_g    = (const float*)d_in[4];
    const float* bn1_b    = (const float*)d_in[5];
    const float* bn1_m    = (const float*)d_in[6];
    const float* bn1_v    = (const float*)d_in[7];
    const float* conv2_w  = (const float*)d_in[8];
    const float* bn2_g    = (const float*)d_in[9];
    const float* bn2_b    = (const float*)d_in[10];
    const float* bn2_m    = (const float*)d_in[11];
    const float* bn2_v    = (const float*)d_in[12];
    const float* conv1d_w = (const float*)d_in[13];
    const float* conv1d_b = (const float*)d_in[14];
    const float* fc1_w    = (const float*)d_in[15];
    const float* fc1_b    = (const float*)d_in[16];
    const float* fc2_w    = (const float*)d_in[17];
    const float* fc2_b    = (const float*)d_in[18];
    float* out = (float*)d_out;

    char* ws = (char*)d_ws;

    // ---- arena (peak ~142.6 MB; proven budget >= 171.7 MB) ----
    float* s1    = (float*)(ws + 0);
    float* t1    = (float*)(ws + 2048);
    float* s2    = (float*)(ws + 4096);
    float* t2    = (float*)(ws + 5120);
    int*   rbid  = (int*)(ws + 6144);          // 4 KB identity (fc1)
    int*   rb1dg = (int*)(ws + 10240);         // 12 KB gathered conv1d taps
    int*   tapm  = (int*)(ws + 22528);         // 308 B per-block tap masks
    int*   rb1t  = (int*)(ws + 25600);         // 355 KB
    int*   rb2t  = (int*)(ws + 380416);        // 355 KB -> 735232
    int*   tasks1 = (int*)(ws + 735232);       // 656 ints -> ends 737856
    int*   tasks2 = (int*)(ws + 738944);       // 260 ints -> ends 739984
    // R_A rotating @ [768000, 60930048): fml -> part1 -> part2 -> part1d -> partfc
    bf16*  fml    = (bf16*)(ws + 768000);
    float* part1  = (float*)(ws + 768000);     // 3 x 9792 x 512 x 4 = 60.16 MB (exact)
    float* part2  = (float*)(ws + 768000);     // 3 x 9792 x 256 x 4 = 30.08 MB
    float* part1d = (float*)(ws + 768000);     // 3 x 1024 x 2304 x 4 = 28.3 MB
    float* partfc = (float*)(ws + 768000);     // 4 x 1024 x 1024 x 4 = 16.8 MB
    // R_B @ 60930048: a1c (zp1 + compact 1088x9x1024) live roi->conv1; then overlaid:
    bf16*  a1c    = (bf16*)(ws + 60930048);    // 2 KB zp + 20.05 MB
    bf16*  wb1d   = (bf16*)(ws + 60930048);    // 31.85 MB (repacked after conv1)
    bf16*  fc1t   = (bf16*)(ws + 92780544);    // 4.72 MB
    bf16*  xbuf   = (bf16*)(ws + 97499136);    // 1024x2304x2 = 4.72 MB
    bf16*  hbuf   = (bf16*)(ws + 102217728);   // 2.10 MB
    bf16*  w2t    = (bf16*)(ws + 104314880);   // 61 KB
    // dedicated
    bf16*  wb1    = (bf16*)(ws + 104857600);   // 9.44 MB
    bf16*  wb2    = (bf16*)(ws + 114294784);   // 2.36 MB
    bf16*  a2c    = (bf16*)(ws + 116654080);   // 1 KB zp + 10.03 MB (pos-major rows)
    bf16*  asm3   = (bf16*)(ws + 126682112);   // 4.6 KB zp + 5.90 MB
    float* feat   = (float*)(ws + 132584960);  // 10.03 MB -> 142611968

    bf16* zp1 = a1c;           // zero pages = buffer prefixes
    bf16* zp2 = a2c;
    bf16* zp3 = asm3;

    // tables + tap masks + static task tables + zero pages + BN folds + w2t
    setup_all<<<(9 * 9856 + 255) / 256, 256, 0, stream>>>(rb1t, rb2t, rb1dg, rbid, tapm,
                                                          tasks1, tasks2, pidx,
                                                          zp1, zp2, zp3,
                                                          bn1_g, bn1_b, bn1_m, bn1_v,
                                                          bn2_g, bn2_b, bn2_m, bn2_v,
                                                          s1, t1, s2, t2, fc2_w, w2t);
    repack_w9_both<<<2560, 256, 0, stream>>>(conv1_w, wb1, conv2_w, wb2);

    transpose_fmap<<<dim3(7, 32, 64), dim3(32, 8), 0, stream>>>(fmap, fml);
    roi_kernel2<<<1088, 128, 0, stream>>>(fml, boxes, a1c);

    // conv1: M=9792 N=512, valid taps only, 656 static LPT tasks (2-3 taps, XCD-interleaved)
    gemm_k<0, 3><<<656, 256, 0, stream>>>(a1c, rb1t, wb1, part1, tapm, tasks1);
    reduce_k<3><<<(9792 * 512 + 255) / 256, 256, 0, stream>>>(part1, a2c, s1, t1, tapm);

    // prep overlaying dead a1c (after conv1)
    repack_w<3><<<(2304 * 2304 + 255) / 256, 256, 0, stream>>>(conv1d_w, wb1d, 2304, 2304);
    transpose_fc1<<<dim3(72, 32), dim3(32, 8), 0, stream>>>(fc1_w, fc1t);

    // conv2: M=9792 N=256, valid taps only, 260 static LPT tasks (3-4 taps, ~1/CU)
    gemm_k<1, 3><<<260, 256, 0, stream>>>(a2c, rb2t, wb2, part2, tapm, tasks2);
    reduce0_tiled<<<1088, 256, 0, stream>>>(part2, feat, s2, t2, tapm);
    assemble<<<dim3(64, 20), 256, 0, stream>>>(feat, pidx, asm3);
    // conv1d at gathered rows: M=1024 N=2304 K=6912, split-K x3 -> 432 blocks (36 steps)
    gemm_k<2, 3><<<dim3(18, 8, 3), 256, 0, stream>>>(asm3, rb1dg, wb1d, part1d, tapm, nullptr);
    reduce_k<1><<<(1024 * 2304 + 255) / 256, 256, 0, stream>>>(part1d, xbuf, conv1d_b, nullptr, nullptr);
    // fc1 (identity rows): M=1024 N=1024 K=2304, split-K x4 -> 256 blocks (exactly 1/CU)
    gemm_k<3, 4><<<dim3(8, 8, 4), 256, 0, stream>>>(xbuf, rbid, fc1t, partfc, tapm, nullptr);
    reduce_k<2><<<(1024 * 1024 + 255) / 256, 256, 0, stream>>>(partfc, hbuf, fc1_b, nullptr, nullptr);
    fc2_kernel<<<128, 256, 0, stream>>>(hbuf, w2t, fc2_b, out);
    (void)in_sizes; (void)n_in; (void)out_size; (void)ws_size;
}

// Round 8
// 445.969 us; speedup vs baseline: 1.0428x; 1.0428x over previous
//
#include <hip/hip_runtime.h>
#include <hip/hip_bf16.h>
#include <cstdint>
#include <cstddef>

typedef __bf16 bf16;
typedef __bf16 bf16x8 __attribute__((ext_vector_type(8)));
typedef float f32x4 __attribute__((ext_vector_type(4)));

// async global->LDS DMA, 16B per lane; lds dest wave-uniform base + lane*16
__device__ __forceinline__ void gload_lds16(const bf16* g, bf16* l) {
    __builtin_amdgcn_global_load_lds((const __attribute__((address_space(1))) void*)g,
                                     (__attribute__((address_space(3))) void*)l, 16, 0, 0);
}

// valid-tap mask for a 128-row pos-major M-block (rows pos*1088+box)
__device__ __forceinline__ int block_tap_mask(int y) {
    int lo = (y * 128) / 1088;
    int hiRow = y * 128 + 127; if (hiRow > 9791) hiRow = 9791;
    int hi = hiRow / 1088;
    int msk = 0;
    for (int pos = lo; pos <= hi; ++pos) {
        int oy = pos / 3, ox = pos - oy * 3;
        int ym = oy == 0 ? 6 : (oy == 1 ? 7 : 3);   // valid ty bits
        int xm = ox == 0 ? 6 : (ox == 1 ? 7 : 3);   // valid tx bits
        #pragma unroll
        for (int ty = 0; ty < 3; ty++)
            #pragma unroll
            for (int tx = 0; tx < 3; tx++)
                if (((ym >> ty) & 1) & ((xm >> tx) & 1))
                    msk |= 1 << (ty * 3 + tx);
    }
    return msk;
}

// ---------------- weight repack (coalesced): w[OC][IC][NT] -> out[OC][NT*IC] bf16
template <int NT>
__global__ void __launch_bounds__(256) repack_w(const float* __restrict__ w, bf16* __restrict__ out,
                                                int OC, int IC) {
    int idx = blockIdx.x * 256 + threadIdx.x;
    if (idx >= OC * IC) return;
    int oc = idx / IC;
    int ic = idx - oc * IC;
    const float* src = w + (size_t)idx * NT;
    #pragma unroll
    for (int t = 0; t < NT; t++)
        out[(size_t)oc * NT * IC + t * IC + ic] = (bf16)src[t];
}

// ---------------- merged conv1+conv2 weight repack (one dispatch)
__global__ void __launch_bounds__(256) repack_w9_both(const float* __restrict__ wa, bf16* __restrict__ oa,
                                                      const float* __restrict__ wb, bf16* __restrict__ ob) {
    int idx = blockIdx.x * 256 + threadIdx.x;
    if (idx < 512 * 1024) {
        int oc = idx >> 10, ic = idx & 1023;
        const float* src = wa + (size_t)idx * 9;
        #pragma unroll
        for (int t = 0; t < 9; t++)
            oa[(size_t)oc * 9216 + t * 1024 + ic] = (bf16)src[t];
    } else {
        int k = idx - 512 * 1024;
        if (k < 256 * 512) {
            int oc = k >> 9, ic = k & 511;
            const float* src = wb + (size_t)k * 9;
            #pragma unroll
            for (int t = 0; t < 9; t++)
                ob[(size_t)oc * 4608 + t * 512 + ic] = (bf16)src[t];
        }
    }
}

// ---------------- fc1_w [2304][1024] -> fc1t [1024][2304] bf16 (LDS tiled)
__global__ void __launch_bounds__(256) transpose_fc1(const float* __restrict__ w, bf16* __restrict__ out) {
    __shared__ float t[32][33];
    int iT = blockIdx.x * 32;
    int oT = blockIdx.y * 32;
    int tx = threadIdx.x, ty = threadIdx.y;   // 32 x 8
    #pragma unroll
    for (int j = 0; j < 4; j++)
        t[ty + j * 8][tx] = w[(size_t)(iT + ty + j * 8) * 1024 + oT + tx];
    __syncthreads();
    #pragma unroll
    for (int j = 0; j < 4; j++)
        out[(size_t)(oT + ty + j * 8) * 2304 + iT + tx] = (bf16)t[tx][ty + j * 8];
}

// ---------------- unified setup: per-tap rowbase tables (POS-MAJOR M), tap masks,
// static LPT task tables, zero pages, BN folds, w2t.
// Shared grouping for conv1/conv2: J = ceil(T/3) (2-3 taps) -> 164 (y,j) entries.
// conv1 tasks = 164 x 4 nt = 656; conv2 = 164 x 2 nt = 328.
// Task order XCD-interleaved: all nt-variants of one (y,j) share blockIdx%8 ->
// same XCD L2 caches the A-tile across n-tiles; LPT (heavy-first) within XCD.
// task pack: (y<<5)|(j<<2)|nt
__global__ void __launch_bounds__(256) setup_all(int* __restrict__ rb1t, int* __restrict__ rb2t,
                                                 int* __restrict__ rb1dg, int* __restrict__ rbid,
                                                 int* __restrict__ tapmask,
                                                 int* __restrict__ tasks1, int* __restrict__ tasks2,
                                                 const int* __restrict__ pidx,
                                                 bf16* __restrict__ zp1, bf16* __restrict__ zp2,
                                                 bf16* __restrict__ zp3,
                                                 const float* g1, const float* b1, const float* m1, const float* v1,
                                                 const float* g2, const float* b2, const float* m2, const float* v2,
                                                 float* __restrict__ s1, float* __restrict__ t1,
                                                 float* __restrict__ s2, float* __restrict__ t2,
                                                 const float* __restrict__ fc2_w, bf16* __restrict__ w2t) {
    int m = blockIdx.x * 256 + threadIdx.x;
    if (m < 9 * 9856) {
        int tap = m / 9856, r = m - tap * 9856;
        int mm = r < 9792 ? r : 0;
        int pos = mm / 1088, img = mm - pos * 1088;     // pos-major decode
        int oy = pos / 3, ox = pos - oy * 3;
        int ty = tap / 3, tx = tap - ty * 3;
        int iy = oy + ty - 1, ix = ox + tx - 1;
        bool valid = (iy >= 0) & (iy < 3) & (ix >= 0) & (ix < 3);
        int cell = iy * 3 + ix;
        rb1t[m] = valid ? 1024 + (img * 9 + cell) * 1024 : 0;     // a1c phys: [box][cell][1024]
        rb2t[m] = valid ? 512 + (cell * 1088 + img) * 512 : 0;    // a2c: pos-major [cell*1088+box][512]
    }
    if (m < 77) tapmask[m] = block_tap_mask(m);
    // ---- block 0: build static LPT-sorted, XCD-interleaved task tables (164 entries)
    if (blockIdx.x == 0) {
        __shared__ int sT[77], sB1[78];
        __shared__ int e1y[164], e1j[164], e1w[164];
        int t = threadIdx.x;
        if (t < 77) sT[t] = __popc(block_tap_mask(t));
        __syncthreads();
        if (t == 0) {
            int a1 = 0;
            for (int y = 0; y < 77; ++y) { sB1[y] = a1; a1 += (sT[y] + 2) / 3; }
            sB1[77] = a1;   // == 164
        }
        __syncthreads();
        if (t < 77) {
            int T = sT[t];
            int J = (T + 2) / 3;
            int w[3] = {0, 0, 0};
            for (int o = 0; o < T; ++o) w[o * J / T]++;
            for (int jj = 0; jj < J; ++jj) {
                int e = sB1[t] + jj;
                e1y[e] = t; e1j[e] = jj; e1w[e] = w[jj];
            }
        }
        __syncthreads();
        if (t < 164) {
            int wv = e1w[t], rank = 0;
            for (int e2i = 0; e2i < 164; ++e2i)
                rank += (e1w[e2i] > wv) | ((e1w[e2i] == wv) & (e2i < t));
            int pk = (e1y[t] << 5) | (e1j[t] << 2);
            #pragma unroll
            for (int nt = 0; nt < 4; ++nt) {
                int idx = (rank < 160) ? ((rank & 7) + (((rank >> 3) * 4 + nt) << 3))
                                       : (640 + (rank - 160) * 4 + nt);
                tasks1[idx] = pk | nt;
            }
            #pragma unroll
            for (int nt = 0; nt < 2; ++nt) {
                int idx = (rank < 160) ? ((rank & 7) + (((rank >> 3) * 2 + nt) << 3))
                                       : (320 + (rank - 160) * 2 + nt);
                tasks2[idx] = pk | nt;
            }
        }
    }
    if (m < 3 * 1024) {
        int tap = m / 1024, r = m - tap * 1024;
        int b = r >> 4;
        int p = pidx[r];
        int tt = b + tap - 1;
        bool valid = (tt >= 0) & (tt < 64);
        rb1dg[m] = valid ? 2304 + (p * 64 + tt) * 2304 : 0;
    }
    if (m < 1024) rbid[m] = m * 2304;
    if (m < 30 * 1024) {
        int n = m / 1024, k = m - n * 1024;
        w2t[m] = (bf16)fc2_w[(size_t)k * 30 + n];
    }
    if (m < 1024) zp1[m] = (bf16)0.f;
    if (m < 512)  zp2[m] = (bf16)0.f;
    if (m < 2304) zp3[m] = (bf16)0.f;
    if (m < 512) {
        float sc = g1[m] * rsqrtf(v1[m] + 1e-5f);
        s1[m] = sc; t1[m] = b1[m] - m1[m] * sc;
    } else if (m < 768) {
        int i = m - 512;
        float sc = g2[i] * rsqrtf(v2[i] + 1e-5f);
        s2[i] = sc; t2[i] = b2[i] - m2[i] * sc;
    }
}

// ---------------- fmap transpose to channels-last bf16
__global__ void __launch_bounds__(256) transpose_fmap(const float* __restrict__ fmap, bf16* __restrict__ fml) {
    __shared__ float t[32][33];
    int img = blockIdx.z;
    int hwT = blockIdx.x * 32;
    int cT  = blockIdx.y * 32;
    int tx = threadIdx.x, ty = threadIdx.y;
    #pragma unroll
    for (int j = 0; j < 4; j++) {
        int c = cT + ty + j * 8;
        int hw = hwT + tx;
        if (hw < 196)
            t[ty + j * 8][tx] = fmap[((size_t)img * 1024 + c) * 196 + hw];
    }
    __syncthreads();
    #pragma unroll
    for (int j = 0; j < 4; j++) {
        int hw = hwT + ty + j * 8;
        int c = cT + tx;
        if (hw < 196)
            fml[((size_t)img * 196 + hw) * 1024 + c] = (bf16)t[tx][ty + j * 8];
    }
}

// ---------------- roi_align (channels-last) -> a1c compact [1088][9][1024] (after 1024-elem zp)
__global__ void __launch_bounds__(128) roi_kernel2(const bf16* __restrict__ fml, const float* __restrict__ boxes,
                                                   bf16* __restrict__ a1c) {
    int box = blockIdx.x;
    int tid = threadIdx.x;
    float x1, y1, x2, y2;
    int img;
    if (box < 64) { img = box; x1 = 0.f; y1 = 0.f; x2 = 14.f; y2 = 14.f; }
    else {
        int ib = box - 64;
        img = ib >> 4;
        const float* bb = boxes + (size_t)ib * 4;
        x1 = bb[0]; y1 = bb[1]; x2 = bb[2]; y2 = bb[3];
    }
    float rw = fmaxf(x2 - x1, 1.f), rh = fmaxf(y2 - y1, 1.f);
    __shared__ float swy[6], swx[6];
    __shared__ int sy0[6], sx0[6];
    if (tid < 6) {
        int i = tid;
        float pos = ((float)i + 0.5f) * 0.5f;
        float yv = fminf(fmaxf(y1 + pos * (rh * (1.f / 3.f)), 0.f), 13.f);
        float y0 = floorf(yv);
        sy0[i] = (int)y0; swy[i] = yv - y0;
        float xv = fminf(fmaxf(x1 + pos * (rw * (1.f / 3.f)), 0.f), 13.f);
        float x0 = floorf(xv);
        sx0[i] = (int)x0; swx[i] = xv - x0;
    }
    __syncthreads();
    const bf16* base = fml + (size_t)img * 196 * 1024 + tid * 8;
    #pragma unroll
    for (int oy = 0; oy < 3; oy++) {
        #pragma unroll
        for (int ox = 0; ox < 3; ox++) {
            float acc[8];
            #pragma unroll
            for (int e = 0; e < 8; e++) acc[e] = 0.f;
            #pragma unroll
            for (int dy = 0; dy < 2; dy++) {
                int sy = 2 * oy + dy;
                int y0 = sy0[sy]; float wy = swy[sy];
                int y1i = min(y0 + 1, 13);
                #pragma unroll
                for (int dx = 0; dx < 2; dx++) {
                    int sx = 2 * ox + dx;
                    int x0 = sx0[sx]; float wx = swx[sx];
                    int x1i = min(x0 + 1, 13);
                    bf16x8 f00 = *(const bf16x8*)(base + (size_t)(y0 * 14 + x0) * 1024);
                    bf16x8 f01 = *(const bf16x8*)(base + (size_t)(y0 * 14 + x1i) * 1024);
                    bf16x8 f10 = *(const bf16x8*)(base + (size_t)(y1i * 14 + x0) * 1024);
                    bf16x8 f11 = *(const bf16x8*)(base + (size_t)(y1i * 14 + x1i) * 1024);
                    float w00 = (1.f - wy) * (1.f - wx), w01 = (1.f - wy) * wx;
                    float w10 = wy * (1.f - wx),         w11 = wy * wx;
                    #pragma unroll
                    for (int e = 0; e < 8; e++)
                        acc[e] += w00 * (float)f00[e] + w01 * (float)f01[e]
                                + w10 * (float)f10[e] + w11 * (float)f11[e];
                }
            }
            bf16x8 o;
            #pragma unroll
            for (int e = 0; e < 8; e++) o[e] = (bf16)(acc[e] * 0.25f);
            *(bf16x8*)(a1c + 1024 + ((size_t)box * 9 + oy * 3 + ox) * 1024 + tid * 8) = o;
        }
    }
}

// ---------------- behavior assembly -> asm3 compact [20][64][2304] (after 2304-elem zp)
__global__ void __launch_bounds__(256) assemble(const float* __restrict__ feat, const int* __restrict__ pidx,
                                                bf16* __restrict__ asm3) {
    int b = blockIdx.x;
    int p = blockIdx.y;
    __shared__ int idxs[16];
    if (threadIdx.x < 16) idxs[threadIdx.x] = pidx[b * 16 + threadIdx.x];
    __syncthreads();
    const float* g = feat + (size_t)b * 2304;
    for (int f = threadIdx.x; f < 2304; f += 256) {
        float v = g[f];
        #pragma unroll
        for (int n = 0; n < 16; n++)
            if (idxs[n] == p) v += feat[(size_t)(64 + b * 16 + n) * 2304 + f];
        asm3[2304 + ((size_t)p * 64 + b) * 2304 + f] = (bf16)v;
    }
}

// ---------------- implicit-GEMM MFMA: 128x128 tile, global_load_lds + XOR swizzle,
// per-tap row tables (zero rows -> zero page). 4 waves 2x2; wave 64x64
// (4x4 16x16x32, acc[4][4]); BK=64; split-K fp32 partials.
// MODE 0/1 (conv1/conv2): POS-MAJOR M + valid-tap skip, static LPT task per block,
// J = ceil(T/3) (2-3 taps). Slices j>=J not written (reducers gate by J).
// MODE 2/3: static grid (uniform K per block).
template <int MODE, int NSPLIT>
__global__ void __launch_bounds__(256) gemm_k(const bf16* __restrict__ A, const int* __restrict__ rowtab,
                                              const bf16* __restrict__ Bw, float* __restrict__ outp,
                                              const int* __restrict__ tapmask,
                                              const int* __restrict__ tasklist) {
    constexpr int K   = MODE == 0 ? 9216 : MODE == 1 ? 4608 : MODE == 2 ? 6912 : 2304;
    constexpr int N   = MODE == 0 ? 512  : MODE == 1 ? 256  : MODE == 2 ? 2304 : 1024;
    constexpr int Cin = MODE == 0 ? 1024 : MODE == 1 ? 512  : 2304;
    constexpr int M   = MODE <= 1 ? 9792 : 1024;
    constexpr int MT  = MODE <= 1 ? 9856 : 1024;   // table row stride
    constexpr bool MPAD = (M % 128) != 0;
    constexpr int KTS = (K / 64) / NSPLIT;

    const int tid = threadIdx.x;
    const int lane = tid & 63, wave = tid >> 6;
    const int q = lane >> 4, ln16 = lane & 15;
    const int wr = wave >> 1, wc = wave & 1;

    __shared__ __align__(16) bf16 As[128 * 64];
    __shared__ __align__(16) bf16 Bs[128 * 64];

    const int sr = lane >> 3;
    const int sc = ((lane & 7) ^ sr) * 8;    // XOR-permuted chunk offset (elems)

    int bm, bn, z;
    int mask = 0, T = 0, J = 0, jsel = 0;
    if constexpr (MODE <= 1) {
        const int pk = tasklist[blockIdx.x];
        const int y = pk >> 5;
        jsel = (pk >> 2) & 7;
        const int nt = pk & 3;
        bm = y * 128; bn = nt * 128; z = jsel;
        mask = tapmask[y];
        T = __popc(mask);
        J = (T + 2) / 3;
    } else {
        bm = blockIdx.y * 128;
        bn = blockIdx.x * 128;
        z = blockIdx.z;
    }

    const bf16* gB[4];
    #pragma unroll
    for (int u = 0; u < 4; u++)
        gB[u] = Bw + (size_t)(bn + wave * 32 + u * 8 + sr) * K + sc;

    f32x4 acc[4][4];
    #pragma unroll
    for (int mt = 0; mt < 4; mt++)
        #pragma unroll
        for (int nn = 0; nn < 4; nn++)
            acc[mt][nn] = (f32x4){0.f, 0.f, 0.f, 0.f};

    if constexpr (MODE <= 1) {
        int ord = 0;
        for (int tap = 0; tap < 9; ++tap) {
            if (!((mask >> tap) & 1)) continue;
            const int o = ord++;
            if (o * J / T != jsel) continue;
            int rbA[4];
            #pragma unroll
            for (int u = 0; u < 4; u++)
                rbA[u] = rowtab[tap * MT + bm + wave * 32 + u * 8 + sr];
            for (int kk = 0; kk < Cin / 64; ++kk) {
                const int aoff = kk * 64 + sc;
                const int k0 = tap * Cin + kk * 64;

                __syncthreads();
                #pragma unroll
                for (int u = 0; u < 4; u++)
                    gload_lds16(A + (size_t)(rbA[u] + aoff), As + (wave * 32 + u * 8) * 64);
                #pragma unroll
                for (int u = 0; u < 4; u++)
                    gload_lds16(gB[u] + k0, Bs + (wave * 32 + u * 8) * 64);
                __syncthreads();

                #pragma unroll
                for (int s = 0; s < 2; s++) {
                    bf16x8 af[4], bfr[4];
                    #pragma unroll
                    for (int mt = 0; mt < 4; mt++) {
                        int r = wr * 64 + mt * 16 + ln16;
                        af[mt] = *(const bf16x8*)(As + r * 64 + (((4 * s + q) ^ (ln16 & 7)) << 3));
                    }
                    #pragma unroll
                    for (int nn = 0; nn < 4; nn++) {
                        int r = wc * 64 + nn * 16 + ln16;
                        bfr[nn] = *(const bf16x8*)(Bs + r * 64 + (((4 * s + q) ^ (ln16 & 7)) << 3));
                    }
                    #pragma unroll
                    for (int mt = 0; mt < 4; mt++)
                        #pragma unroll
                        for (int nn = 0; nn < 4; nn++)
                            acc[mt][nn] = __builtin_amdgcn_mfma_f32_16x16x32_bf16(af[mt], bfr[nn], acc[mt][nn], 0, 0, 0);
                }
            }
        }
    } else {
        int rbA[4];
        int curtap = -1;
        for (int kt = z * KTS; kt < z * KTS + KTS; kt++) {
            const int k0 = kt * 64;
            const int tap = k0 / Cin;                 // wave-uniform
            const int inner = k0 - tap * Cin;
            if (tap != curtap) {
                curtap = tap;
                #pragma unroll
                for (int u = 0; u < 4; u++)
                    rbA[u] = rowtab[tap * MT + bm + wave * 32 + u * 8 + sr];
            }
            const int aoff = inner + sc;

            __syncthreads();
            #pragma unroll
            for (int u = 0; u < 4; u++)
                gload_lds16(A + (size_t)(rbA[u] + aoff), As + (wave * 32 + u * 8) * 64);
            #pragma unroll
            for (int u = 0; u < 4; u++)
                gload_lds16(gB[u] + k0, Bs + (wave * 32 + u * 8) * 64);
            __syncthreads();

            #pragma unroll
            for (int s = 0; s < 2; s++) {
                bf16x8 af[4], bfr[4];
                #pragma unroll
                for (int mt = 0; mt < 4; mt++) {
                    int r = wr * 64 + mt * 16 + ln16;
                    af[mt] = *(const bf16x8*)(As + r * 64 + (((4 * s + q) ^ (ln16 & 7)) << 3));
                }
                #pragma unroll
                for (int nn = 0; nn < 4; nn++) {
                    int r = wc * 64 + nn * 16 + ln16;
                    bfr[nn] = *(const bf16x8*)(Bs + r * 64 + (((4 * s + q) ^ (ln16 & 7)) << 3));
                }
                #pragma unroll
                for (int mt = 0; mt < 4; mt++)
                    #pragma unroll
                    for (int nn = 0; nn < 4; nn++)
                        acc[mt][nn] = __builtin_amdgcn_mfma_f32_16x16x32_bf16(af[mt], bfr[nn], acc[mt][nn], 0, 0, 0);
            }
        }
    }

    // epilogue: C/D layout col=lane&15, row=quad*4+reg; fp32 partials
    #pragma unroll
    for (int mt = 0; mt < 4; mt++) {
        int gmBase = bm + wr * 64 + mt * 16 + q * 4;
        #pragma unroll
        for (int r = 0; r < 4; r++) {
            int gm = gmBase + r;
            if (MPAD && gm >= M) continue;
            #pragma unroll
            for (int nn = 0; nn < 4; nn++) {
                int gn = bn + wc * 64 + nn * 16 + ln16;
                outp[((size_t)z * M + gm) * N + gn] = acc[mt][nn][r];
            }
        }
    }
}

// ---------------- conv2 reducer: per-cell block, coalesced + LDS transpose
// part2[<=3][9792][256] (POS-MAJOR rows: pos*1088+cell) -> feat[1088][2304] fp32
// with BN+leaky, f = oc*9+pos. Slice count per row = J(y) = ceil(T/3) in {2,3}.
__global__ void __launch_bounds__(256) reduce0_tiled(const float* __restrict__ part,
                                                     float* __restrict__ feat,
                                                     const float* __restrict__ s2, const float* __restrict__ t2,
                                                     const int* __restrict__ tapm) {
    int c = blockIdx.x;            // cell 0..1087
    int t = threadIdx.x;           // oc
    float acc[9];
    #pragma unroll
    for (int r = 0; r < 9; r++) {
        int m = r * 1088 + c;
        int y = m >> 7;
        int J = (__popc(tapm[y]) + 2) / 3;           // 2 or 3
        const float* p0 = part + (size_t)m * 256 + t;
        float v = p0[0] + p0[(size_t)9792 * 256];
        if (J == 3) v += p0[(size_t)2 * 9792 * 256];
        acc[r] = v;
    }
    float s = s2[t], b = t2[t];
    __shared__ float L[9 * 257];
    #pragma unroll
    for (int r = 0; r < 9; r++) {
        float v = acc[r] * s + b;
        v = v > 0.f ? v : 0.1f * v;
        L[r * 257 + t] = v;        // L[pos*257 + oc]
    }
    __syncthreads();
    float* fout = feat + (size_t)c * 2304;
    #pragma unroll
    for (int k = 0; k < 9; k++) {
        int f = t + k * 256;
        int oc = f / 9, pos = f - oc * 9;
        fout[f] = L[pos * 257 + oc];
    }
}

// ---------------- split-K reducers
// RMODE 1: conv1d -> xbuf bf16 (+bias, linear [m=(b,n)][oc]), S=3, M=1024 N=2304
// RMODE 3: conv1 -> a2c compact bf16 (BN+leaky, +zp offset), slices=J(y) in {2,3}
template <int RMODE>
__global__ void __launch_bounds__(256) reduce_k(const float* __restrict__ part, void* __restrict__ outp,
                                                const float* __restrict__ c0, const float* __restrict__ c1,
                                                const int* __restrict__ tapm) {
    constexpr int M = RMODE == 1 ? 1024 : 9792;
    constexpr int N = RMODE == 1 ? 2304 : 512;
    constexpr int S = RMODE == 1 ? 3    : 2;
    int idx = blockIdx.x * 256 + threadIdx.x;
    if (idx >= M * N) return;
    int m = idx / N, n = idx - m * N;
    float v = 0.f;
    #pragma unroll
    for (int s = 0; s < S; s++) v += part[(size_t)s * M * N + idx];
    if constexpr (RMODE == 1) {
        v += c0[n];
        ((bf16*)outp)[idx] = (bf16)v;
    } else {
        int y = m >> 7;
        int J = (__popc(tapm[y]) + 2) / 3;           // 2 or 3
        if (J == 3) v += part[(size_t)2 * M * N + idx];
        v = v * c0[n] + c1[n];
        v = v > 0.f ? v : 0.1f * v;
        ((bf16*)outp)[512 + (size_t)m * 512 + n] = (bf16)v;   // compact, after zp2
    }
}

// ---------------- fused fc1-reduce + fc2: one block per m-row.
// partfc[4][1024][1024] -> h (LDS, relu+bias) -> out[m][30] = h @ w2t^T + fc2_b
__global__ void __launch_bounds__(256) fc1red_fc2(const float* __restrict__ part,
                                                  const float* __restrict__ b1,
                                                  const bf16* __restrict__ w2t,
                                                  const float* __restrict__ b2,
                                                  float* __restrict__ out) {
    int m = blockIdx.x;            // 0..1023
    int t = threadIdx.x;
    __shared__ float h[1024];
    __shared__ float red[256];
    #pragma unroll
    for (int i = 0; i < 4; i++) {
        int k = t + i * 256;
        float v = 0.f;
        #pragma unroll
        for (int s = 0; s < 4; s++) v += part[((size_t)s * 1024 + m) * 1024 + k];
        h[k] = fmaxf(v + b1[k], 0.f);
    }
    __syncthreads();
    // n = t&31 (30 used), chunk c = t>>5 (8 chunks of 128): 2-way LDS aliasing max
    {
        int c = t >> 5, n = t & 31;
        float acc = 0.f;
        if (n < 30) {
            const bf16* wr = w2t + (size_t)n * 1024 + c * 128;
            const float* hh = h + c * 128;
            #pragma unroll
            for (int k = 0; k < 128; k++) acc += hh[k] * (float)wr[k];
        }
        red[t] = acc;
    }
    __syncthreads();
    if (t < 30) {
        float acc = 0.f;
        #pragma unroll
        for (int c = 0; c < 8; c++) acc += red[c * 32 + t];
        out[(size_t)m * 30 + t] = acc + b2[t];
    }
}

extern "C" void kernel_launch(void* const* d_in, const int* in_sizes, int n_in,
                              void* d_out, int out_size, void* d_ws, size_t ws_size,
                              hipStream_t stream) {
    const float* fmap     = (const float*)d_in[0];
    const float* boxes    = (const float*)d_in[1];
    const int*   pidx     = (const int*)d_in[2];
    const float* conv1_w  = (const float*)d_in[3];
    const float* bn1_g    = (const float*)d_in[4];
    const float* bn1_b    = (const float*)d_in[5];
    const float* bn1_m    = (const float*)d_in[6];
    const float* bn1_v    = (const float*)d_in[7];
    const float* conv2_w  = (const float*)d_in[8];
    const float* bn2_g    = (const float*)d_in[9];
    const float* bn2_b    = (const float*)d_in[10];
    const float* bn2_m    = (const float*)d_in[11];
    const float* bn2_v    = (const float*)d_in[12];
    const float* conv1d_w = (const float*)d_in[13];
    const float* conv1d_b = (const float*)d_in[14];
    const float* fc1_w    = (const float*)d_in[15];
    const float* fc1_b    = (const float*)d_in[16];
    const float* fc2_w    = (const float*)d_in[17];
    const float* fc2_b    = (const float*)d_in[18];
    float* out = (float*)d_out;

    char* ws = (char*)d_ws;

    // ---- arena (peak ~142.6 MB; proven budget >= 171.7 MB) ----
    float* s1    = (float*)(ws + 0);
    float* t1    = (float*)(ws + 2048);
    float* s2    = (float*)(ws + 4096);
    float* t2    = (float*)(ws + 5120);
    int*   rbid  = (int*)(ws + 6144);          // 4 KB identity (fc1)
    int*   rb1dg = (int*)(ws + 10240);         // 12 KB gathered conv1d taps
    int*   tapm  = (int*)(ws + 22528);         // 308 B per-block tap masks
    int*   rb1t  = (int*)(ws + 25600);         // 355 KB
    int*   rb2t  = (int*)(ws + 380416);        // 355 KB -> 735232
    int*   tasks1 = (int*)(ws + 735232);       // 656 ints -> ends 737856
    int*   tasks2 = (int*)(ws + 738944);       // 328 ints -> ends 740256
    // R_A rotating @ [768000, 60930048): fml -> part1 -> part2 -> part1d -> partfc
    bf16*  fml    = (bf16*)(ws + 768000);
    float* part1  = (float*)(ws + 768000);     // 3 x 9792 x 512 x 4 = 60.16 MB (exact)
    float* part2  = (float*)(ws + 768000);     // 3 x 9792 x 256 x 4 = 30.08 MB
    float* part1d = (float*)(ws + 768000);     // 3 x 1024 x 2304 x 4 = 28.3 MB
    float* partfc = (float*)(ws + 768000);     // 4 x 1024 x 1024 x 4 = 16.8 MB
    // R_B @ 60930048: a1c (zp1 + compact 1088x9x1024) live roi->conv1; then overlaid:
    bf16*  a1c    = (bf16*)(ws + 60930048);    // 2 KB zp + 20.05 MB
    bf16*  wb1d   = (bf16*)(ws + 60930048);    // 31.85 MB (repacked after conv1)
    bf16*  fc1t   = (bf16*)(ws + 92780544);    // 4.72 MB
    bf16*  xbuf   = (bf16*)(ws + 97499136);    // 1024x2304x2 = 4.72 MB
    bf16*  w2t    = (bf16*)(ws + 104314880);   // 61 KB
    // dedicated
    bf16*  wb1    = (bf16*)(ws + 104857600);   // 9.44 MB
    bf16*  wb2    = (bf16*)(ws + 114294784);   // 2.36 MB
    bf16*  a2c    = (bf16*)(ws + 116654080);   // 1 KB zp + 10.03 MB (pos-major rows)
    bf16*  asm3   = (bf16*)(ws + 126682112);   // 4.6 KB zp + 5.90 MB
    float* feat   = (float*)(ws + 132584960);  // 10.03 MB -> 142611968

    bf16* zp1 = a1c;           // zero pages = buffer prefixes
    bf16* zp2 = a2c;
    bf16* zp3 = asm3;

    // tables + tap masks + static task tables + zero pages + BN folds + w2t
    setup_all<<<(9 * 9856 + 255) / 256, 256, 0, stream>>>(rb1t, rb2t, rb1dg, rbid, tapm,
                                                          tasks1, tasks2, pidx,
                                                          zp1, zp2, zp3,
                                                          bn1_g, bn1_b, bn1_m, bn1_v,
                                                          bn2_g, bn2_b, bn2_m, bn2_v,
                                                          s1, t1, s2, t2, fc2_w, w2t);
    repack_w9_both<<<2560, 256, 0, stream>>>(conv1_w, wb1, conv2_w, wb2);

    transpose_fmap<<<dim3(7, 32, 64), dim3(32, 8), 0, stream>>>(fmap, fml);
    roi_kernel2<<<1088, 128, 0, stream>>>(fml, boxes, a1c);

    // conv1: M=9792 N=512, valid taps only, 656 static LPT tasks (2-3 taps, XCD-interleaved)
    gemm_k<0, 3><<<656, 256, 0, stream>>>(a1c, rb1t, wb1, part1, tapm, tasks1);
    reduce_k<3><<<(9792 * 512 + 255) / 256, 256, 0, stream>>>(part1, a2c, s1, t1, tapm);

    // prep overlaying dead a1c (after conv1)
    repack_w<3><<<(2304 * 2304 + 255) / 256, 256, 0, stream>>>(conv1d_w, wb1d, 2304, 2304);
    transpose_fc1<<<dim3(72, 32), dim3(32, 8), 0, stream>>>(fc1_w, fc1t);

    // conv2: M=9792 N=256, valid taps only, 328 static LPT tasks (2-3 taps, XCD-interleaved)
    gemm_k<1, 3><<<328, 256, 0, stream>>>(a2c, rb2t, wb2, part2, tapm, tasks2);
    reduce0_tiled<<<1088, 256, 0, stream>>>(part2, feat, s2, t2, tapm);
    assemble<<<dim3(64, 20), 256, 0, stream>>>(feat, pidx, asm3);
    // conv1d at gathered rows: M=1024 N=2304 K=6912, split-K x3 -> 432 blocks (36 steps)
    gemm_k<2, 3><<<dim3(18, 8, 3), 256, 0, stream>>>(asm3, rb1dg, wb1d, part1d, tapm, nullptr);
    reduce_k<1><<<(1024 * 2304 + 255) / 256, 256, 0, stream>>>(part1d, xbuf, conv1d_b, nullptr, nullptr);
    // fc1 (identity rows): M=1024 N=1024 K=2304, split-K x4 -> 256 blocks (exactly 1/CU)
    gemm_k<3, 4><<<dim3(8, 8, 4), 256, 0, stream>>>(xbuf, rbid, fc1t, partfc, tapm, nullptr);
    // fused fc1-reduce + fc2 (replaces reduce_k<2> + fc2_kernel, drops hbuf round-trip)
    fc1red_fc2<<<1024, 256, 0, stream>>>(partfc, fc1_b, w2t, fc2_b, out);
    (void)in_sizes; (void)n_in; (void)out_size; (void)ws_size;
}